// Round 2
// baseline (559.607 us; speedup 1.0000x reference)
//
#include <hip/hip_runtime.h>
#include <hip/hip_bf16.h>
#include <math.h>

// Problem constants (match reference)
#define B 8
#define L 2048
#define H 2048
#define NA 8
#define NEG_INF (-1e30f)

#define HCHUNKS 32
#define HC_SZ (H / HCHUNKS)   // 64

__device__ __forceinline__ float sigf(float t) {
    return 1.0f / (1.0f + __expf(-t));
}

// Kernel A: partial Wy[b, hc, x] = sum_{h in chunk hc} y[b,h]*weight[h,x]*sig(wa[a_b,h,x])
// + fused last-block reduction: Wy[b,x] = sum_hc partial + bias[x]*sig(ba[a_b,x])
// grid: (B*2, HCHUNKS), block 256. Each thread handles 4 consecutive x (float4).
__global__ __launch_bounds__(256) void k_wy(
    const float* __restrict__ y, const int* __restrict__ actions,
    const float* __restrict__ weight, const float* __restrict__ wa,
    const float* __restrict__ bias, const float* __restrict__ ba,
    float* __restrict__ partial, float* __restrict__ Wy, int* __restrict__ cnt)
{
    const int bx = blockIdx.x;            // b*2 + xtile
    const int hc = blockIdx.y;            // 0..HCHUNKS-1
    const int b  = bx >> 1;
    const int xt = bx & 1;
    const int x0 = xt * 1024 + threadIdx.x * 4;
    const int a  = actions[b];
    const int h0 = hc * HC_SZ;

    const float* __restrict__ yb     = y + b * H;
    const float* __restrict__ wbase  = weight + (size_t)h0 * H + x0;
    const float* __restrict__ wabase = wa + ((size_t)a * H + h0) * H + x0;

    float4 acc = make_float4(0.f, 0.f, 0.f, 0.f);
    #pragma unroll 8
    for (int i = 0; i < HC_SZ; ++i) {
        const float  yv = yb[h0 + i];
        const float4 w4 = *(const float4*)(wbase  + (size_t)i * H);
        const float4 a4 = *(const float4*)(wabase + (size_t)i * H);
        acc.x += yv * w4.x * sigf(a4.x);
        acc.y += yv * w4.y * sigf(a4.y);
        acc.z += yv * w4.z * sigf(a4.z);
        acc.w += yv * w4.w * sigf(a4.w);
    }
    *(float4*)(partial + ((size_t)(b * HCHUNKS + hc) * H) + x0) = acc;

    // ---- last-block-per-(b,xt) does the deterministic fixed-order reduce ----
    __threadfence();                               // device-scope release of partial
    __shared__ int amLast;
    if (threadIdx.x == 0)
        amLast = (atomicAdd(&cnt[bx], 1) == HCHUNKS - 1);
    __syncthreads();
    if (!amLast) return;
    __threadfence();                               // acquire: see all partials

    float4 s = make_float4(0.f, 0.f, 0.f, 0.f);
    const float* __restrict__ p = partial + (size_t)b * HCHUNKS * H + x0;
    #pragma unroll 8
    for (int c = 0; c < HCHUNKS; ++c) {            // fixed order -> deterministic
        const float4 v = *(const float4*)(p + (size_t)c * H);
        s.x += v.x; s.y += v.y; s.z += v.z; s.w += v.w;
    }
    const float4 bi  = *(const float4*)(bias + x0);
    const float4 bav = *(const float4*)(ba + (size_t)a * H + x0);
    s.x += bi.x * sigf(bav.x);
    s.y += bi.y * sigf(bav.y);
    s.z += bi.z * sigf(bav.z);
    s.w += bi.w * sigf(bav.w);
    *(float4*)(Wy + (size_t)b * H + x0) = s;

    if (threadIdx.x == 0) cnt[bx] = 0;             // steady-state zero for next call
}

// Kernel B: xWy[b,l] = sum_h x[b,l,h]*Wy[b,h] (+mask), one wave per row,
// + fused last-block-per-b softmax over L.
// grid: B*L/4 blocks x 256 threads (4 waves/block; a block never straddles b).
__global__ __launch_bounds__(256) void k_xwy_sm(
    const float* __restrict__ x, const float* __restrict__ Wy,
    const unsigned char* __restrict__ mask, float* __restrict__ xWy,
    float* __restrict__ out, int* __restrict__ cnt)
{
    const int wave = threadIdx.x >> 6;
    const int lane = threadIdx.x & 63;
    const int row  = blockIdx.x * 4 + wave;        // 0..B*L-1
    const int b    = (blockIdx.x * 4) >> 11;       // uniform per block

    const float* __restrict__ xb = x + (size_t)row * H;
    const float* __restrict__ wy = Wy + (size_t)b * H;

    float acc = 0.f;
    #pragma unroll
    for (int j = 0; j < H / 256; ++j) {            // 8 iters
        const int off = j * 256 + lane * 4;
        const float4 xv = *(const float4*)(xb + off);
        const float4 wv = *(const float4*)(wy + off);
        acc += xv.x * wv.x + xv.y * wv.y + xv.z * wv.z + xv.w * wv.w;
    }
    #pragma unroll
    for (int s = 32; s; s >>= 1) acc += __shfl_xor(acc, s, 64);
    if (lane == 0) xWy[row] = mask[row] ? NEG_INF : acc;

    // ---- last-block-per-b does the softmax ----
    __threadfence();
    __shared__ int amLast;
    if (threadIdx.x == 0)
        amLast = (atomicAdd(&cnt[b], 1) == (L / 4) - 1);
    __syncthreads();
    if (!amLast) return;
    __threadfence();

    const int tid = threadIdx.x;
    const float* __restrict__ v = xWy + (size_t)b * L;

    float vals[L / 256];
    float m = -INFINITY;
    #pragma unroll
    for (int j = 0; j < L / 256; ++j) {
        vals[j] = v[tid + j * 256];
        m = fmaxf(m, vals[j]);
    }
    #pragma unroll
    for (int s = 32; s; s >>= 1) m = fmaxf(m, __shfl_xor(m, s, 64));

    __shared__ float redm[4];
    if (lane == 0) redm[wave] = m;
    __syncthreads();
    m = fmaxf(fmaxf(redm[0], redm[1]), fmaxf(redm[2], redm[3]));

    float sum = 0.f;
    #pragma unroll
    for (int j = 0; j < L / 256; ++j) {
        vals[j] = __expf(vals[j] - m);
        sum += vals[j];
    }
    #pragma unroll
    for (int s = 32; s; s >>= 1) sum += __shfl_xor(sum, s, 64);

    __shared__ float reds[4];
    if (lane == 0) reds[wave] = sum;
    __syncthreads();
    sum = reds[0] + reds[1] + reds[2] + reds[3];

    const float inv = 1.0f / sum;
    #pragma unroll
    for (int j = 0; j < L / 256; ++j)
        out[(size_t)b * L + tid + j * 256] = vals[j] * inv;

    if (threadIdx.x == 0) cnt[b] = 0;
}

extern "C" void kernel_launch(void* const* d_in, const int* in_sizes, int n_in,
                              void* d_out, int out_size, void* d_ws, size_t ws_size,
                              hipStream_t stream) {
    const float*         x       = (const float*)d_in[0];
    const float*         y       = (const float*)d_in[1];
    const unsigned char* mask    = (const unsigned char*)d_in[2];
    const int*           actions = (const int*)d_in[3];
    const float*         weight  = (const float*)d_in[4];
    const float*         bias    = (const float*)d_in[5];
    const float*         wa      = (const float*)d_in[6];
    const float*         ba      = (const float*)d_in[7];
    float*               out     = (float*)d_out;

    float* ws      = (float*)d_ws;
    float* partial = ws;                                // B*HCHUNKS*H floats = 2 MiB
    float* Wy      = partial + (size_t)B * HCHUNKS * H; // B*H floats
    float* xWy     = Wy + (size_t)B * H;                // B*L floats
    int*   cnt     = (int*)(xWy + (size_t)B * L);       // 16 ints (k_wy) + 8 ints (k_xwy_sm)
    int*   cntA    = cnt;
    int*   cntB    = cnt + 16;

    // ws is poisoned 0xAA once by the harness; counters must start at 0.
    // (kernels self-reset them to 0 at the end of each call.)
    hipMemsetAsync(cnt, 0, 128, stream);

    dim3 g1(B * 2, HCHUNKS);
    k_wy<<<g1, 256, 0, stream>>>(y, actions, weight, wa, bias, ba, partial, Wy, cntA);
    k_xwy_sm<<<B * L / 4, 256, 0, stream>>>(x, Wy, mask, xWy, out, cntB);
}

// Round 3
// 54.902 us; speedup vs baseline: 10.1928x; 10.1928x over previous
//
#include <hip/hip_runtime.h>
#include <hip/hip_bf16.h>
#include <math.h>

// Problem constants (match reference)
#define B 8
#define L 2048
#define H 2048
#define NA 8
#define NEG_INF (-1e30f)

#define XT 64          // blocks per b along x
#define COLS 32        // x-columns per block (8 float4)

__device__ __forceinline__ float sigf(float t) {
    return 1.0f / (1.0f + __expf(-t));
}

// Kernel 1 (fused): Wy[b,x] = sum_h y[b,h]*weight[h,x]*sig(wa[a_b,h,x]) + bias[x]*sig(ba[a_b,x])
// grid (XT, B) = 512 blocks, 256 threads.
// Thread (hg = t>>3, c4 = t&7) accumulates rows h = hg, hg+32, ... for 4 cols;
// block-internal LDS tree reduce over the 32 h-groups (deterministic, no atomics).
__global__ __launch_bounds__(256) void k_wy(
    const float* __restrict__ y, const int* __restrict__ actions,
    const float* __restrict__ weight, const float* __restrict__ wa,
    const float* __restrict__ bias, const float* __restrict__ ba,
    float* __restrict__ Wy)
{
    const int b  = blockIdx.y;
    const int x0 = blockIdx.x * COLS;
    const int a  = actions[b];
    const int c4 = threadIdx.x & 7;      // float4 column within block
    const int hg = threadIdx.x >> 3;     // 0..31

    __shared__ float ylds[H];            // 8 KB
    for (int i = threadIdx.x * 4; i < H; i += 1024)
        *(float4*)(ylds + i) = *(const float4*)(y + (size_t)b * H + i);
    __syncthreads();

    const float* __restrict__ wp = weight + x0 + c4 * 4;
    const float* __restrict__ ap = wa + (size_t)a * H * H + x0 + c4 * 4;

    float4 acc = make_float4(0.f, 0.f, 0.f, 0.f);
    #pragma unroll 8
    for (int h = hg; h < H; h += 32) {
        const float  yv = ylds[h];
        const float4 w4 = *(const float4*)(wp + (size_t)h * H);
        const float4 a4 = *(const float4*)(ap + (size_t)h * H);
        acc.x += yv * w4.x * sigf(a4.x);
        acc.y += yv * w4.y * sigf(a4.y);
        acc.z += yv * w4.z * sigf(a4.z);
        acc.w += yv * w4.w * sigf(a4.w);
    }

    __shared__ float4 red[32][8];        // 4 KB
    red[hg][c4] = acc;
    __syncthreads();
    #pragma unroll
    for (int s = 16; s; s >>= 1) {
        if (hg < s) {
            const float4 v = red[hg + s][c4];
            acc.x += v.x; acc.y += v.y; acc.z += v.z; acc.w += v.w;
            red[hg][c4] = acc;
        }
        __syncthreads();
    }

    if (hg == 0) {
        const float4 bi  = *(const float4*)(bias + x0 + c4 * 4);
        const float4 bav = *(const float4*)(ba + (size_t)a * H + x0 + c4 * 4);
        acc.x += bi.x * sigf(bav.x);
        acc.y += bi.y * sigf(bav.y);
        acc.z += bi.z * sigf(bav.z);
        acc.w += bi.w * sigf(bav.w);
        *(float4*)(Wy + (size_t)b * H + x0 + c4 * 4) = acc;
    }
}

// Kernel 2: xWy[b,l] = sum_h x[b,l,h]*Wy[b,h] (+mask). One wave per row, Wy staged in LDS.
// grid: B*L/4 blocks x 256 threads (4 waves/block; block never straddles b).
__global__ __launch_bounds__(256) void k_xwy(
    const float* __restrict__ x, const float* __restrict__ Wy,
    const unsigned char* __restrict__ mask, float* __restrict__ xWy)
{
    const int wave = threadIdx.x >> 6;
    const int lane = threadIdx.x & 63;
    const int row  = blockIdx.x * 4 + wave;        // 0..B*L-1
    const int b    = (blockIdx.x * 4) >> 11;       // uniform per block

    __shared__ float wlds[H];                      // 8 KB
    for (int i = threadIdx.x * 4; i < H; i += 1024)
        *(float4*)(wlds + i) = *(const float4*)(Wy + (size_t)b * H + i);
    __syncthreads();

    const float* __restrict__ xb = x + (size_t)row * H;

    float acc = 0.f;
    #pragma unroll
    for (int j = 0; j < H / 256; ++j) {            // 8 iters
        const int off = j * 256 + lane * 4;
        const float4 xv = *(const float4*)(xb + off);
        const float4 wv = *(const float4*)(wlds + off);
        acc += xv.x * wv.x + xv.y * wv.y + xv.z * wv.z + xv.w * wv.w;
    }
    #pragma unroll
    for (int s = 32; s; s >>= 1) acc += __shfl_xor(acc, s, 64);
    if (lane == 0) xWy[row] = mask[row] ? NEG_INF : acc;
}

// Kernel 3: softmax over L per batch row. grid: B blocks x 256 threads (8 elems/thread).
__global__ __launch_bounds__(256) void k_softmax(
    const float* __restrict__ xWy, float* __restrict__ out)
{
    const int b    = blockIdx.x;
    const int tid  = threadIdx.x;
    const int wave = tid >> 6;
    const int lane = tid & 63;
    const float* __restrict__ v = xWy + (size_t)b * L;

    float vals[L / 256];
    float m = -INFINITY;
    #pragma unroll
    for (int j = 0; j < L / 256; ++j) {
        vals[j] = v[tid + j * 256];
        m = fmaxf(m, vals[j]);
    }
    #pragma unroll
    for (int s = 32; s; s >>= 1) m = fmaxf(m, __shfl_xor(m, s, 64));

    __shared__ float redm[4];
    if (lane == 0) redm[wave] = m;
    __syncthreads();
    m = fmaxf(fmaxf(redm[0], redm[1]), fmaxf(redm[2], redm[3]));

    float sum = 0.f;
    #pragma unroll
    for (int j = 0; j < L / 256; ++j) {
        vals[j] = __expf(vals[j] - m);
        sum += vals[j];
    }
    #pragma unroll
    for (int s = 32; s; s >>= 1) sum += __shfl_xor(sum, s, 64);

    __shared__ float reds[4];
    if (lane == 0) reds[wave] = sum;
    __syncthreads();
    sum = reds[0] + reds[1] + reds[2] + reds[3];

    const float inv = 1.0f / sum;
    #pragma unroll
    for (int j = 0; j < L / 256; ++j)
        out[(size_t)b * L + tid + j * 256] = vals[j] * inv;
}

extern "C" void kernel_launch(void* const* d_in, const int* in_sizes, int n_in,
                              void* d_out, int out_size, void* d_ws, size_t ws_size,
                              hipStream_t stream) {
    const float*         x       = (const float*)d_in[0];
    const float*         y       = (const float*)d_in[1];
    const unsigned char* mask    = (const unsigned char*)d_in[2];
    const int*           actions = (const int*)d_in[3];
    const float*         weight  = (const float*)d_in[4];
    const float*         bias    = (const float*)d_in[5];
    const float*         wa      = (const float*)d_in[6];
    const float*         ba      = (const float*)d_in[7];
    float*               out     = (float*)d_out;

    float* ws  = (float*)d_ws;
    float* Wy  = ws;                        // B*H floats
    float* xWy = Wy + (size_t)B * H;        // B*L floats

    dim3 g1(XT, B);
    k_wy<<<g1, 256, 0, stream>>>(y, actions, weight, wa, bias, ba, Wy);
    k_xwy<<<B * L / 4, 256, 0, stream>>>(x, Wy, mask, xWy);
    k_softmax<<<B, 256, 0, stream>>>(xWy, out);
}